// Round 5
// baseline (103.074 us; speedup 1.0000x reference)
//
#include <hip/hip_runtime.h>
#include <hip/hip_bf16.h>

typedef __attribute__((ext_vector_type(8))) short bf16x8;    // 8 bf16 = 4 VGPRs
typedef __attribute__((ext_vector_type(4))) float f32x4;
typedef __attribute__((ext_vector_type(16))) float f32x16;

#define BN 8192          // batch
#define DF 128           // feature dim
#define DG 64            // gathered dim
static constexpr float L2E = 1.44269504088896340736f;  // log2(e)
static constexpr float LN2 = 0.69314718055994530942f;

// Fragment-linear layout for 32x32x16 MFMA tiles (R10, kept).
// Per 32-row tile (2048 shorts = 4KB): element (row, k) lives at
//   tile*2048 + (k>>4)*512 + ((((k>>3)&1)*32 + (row&31))*8) + (k&7)
// i.e. lane = (k_hi8)*32 + m, elem c = k&7 -- canonical A/B layout for
// v_mfma_f32_32x32x16_bf16; a wave's fragment load for K-step kk is
// base + kk*512 shorts + lane*16B -> contiguous 1KB.
__device__ __forceinline__ size_t frag_off32(int row, int d) {
  int tile = row >> 5;
  int kk = d >> 4, khi = (d >> 3) & 1, c = d & 7;
  return (size_t)tile * 2048 + (size_t)kk * 512 +
         (size_t)(khi * 32 + (row & 31)) * 8 + c;
}

// ---------------------------------------------------------------------------
// Kernel 1: gather columns, convert to bf16 (X-side pre-scaled by log2 e),
// write 32-row fragment-linear layout, exact fp32 diagonals, zero rowsum/out.
// One wave per row; coalesced float2 row loads + in-register __shfl gather.
// ---------------------------------------------------------------------------
__global__ __launch_bounds__(256) void gather_k(
    const float* __restrict__ a, const float* __restrict__ v,
    const int* __restrict__ aidx, const int* __restrict__ iidx,
    __hip_bfloat16* __restrict__ Xv, __hip_bfloat16* __restrict__ Ya,
    __hip_bfloat16* __restrict__ Xa, __hip_bfloat16* __restrict__ Yv,
    float* __restrict__ diag, float* __restrict__ rowsum,
    float* __restrict__ out) {
  int tid = threadIdx.x;
  int gid = blockIdx.x * 256 + tid;
  if (gid < 2 * BN) rowsum[gid] = 0.f;    // zero accumulators (ws is poisoned)
  if (gid == 0) out[0] = 0.f;             // d_out is poisoned too

  int lane = tid & 63;
  int row  = blockIdx.x * 4 + (tid >> 6); // 2048 blocks x 4 waves = 8192 rows
  int ka = aidx[lane];
  int ki = iidx[lane];

  // coalesced: lane l holds elements (2l, 2l+1) of this row of a and v
  float2 a2 = ((const float2*)(a + (size_t)row * DF))[lane];
  float2 v2 = ((const float2*)(v + (size_t)row * DF))[lane];

  // in-register gather: element k lives in lane k>>1, component k&1
  float axa = __shfl(a2.x, ka >> 1), aya = __shfl(a2.y, ka >> 1);
  float vxa = __shfl(v2.x, ka >> 1), vya = __shfl(v2.y, ka >> 1);
  float axi = __shfl(a2.x, ki >> 1), ayi = __shfl(a2.y, ki >> 1);
  float vxi = __shfl(v2.x, ki >> 1), vyi = __shfl(v2.y, ki >> 1);
  float aa = (ka & 1) ? aya : axa;   // audio_only        (S_v cols)
  float va = (ka & 1) ? vya : vxa;   // image_audio_only  (S_v rows)
  float ai = (ki & 1) ? ayi : axi;   // audio_image_only  (S_a rows)
  float vi = (ki & 1) ? vyi : vxi;   // image_only        (S_a cols)

  size_t fo = frag_off32(row, lane);
  Xv[fo] = __float2bfloat16(va * L2E);
  Ya[fo] = __float2bfloat16(aa);
  Xa[fo] = __float2bfloat16(ai * L2E);
  Yv[fo] = __float2bfloat16(vi);

  // exact fp32 diagonals: diag_v[i] = dot(v_gath_a[i], a_gath_a[i]), etc.
  float dv = va * aa;
  float da = ai * vi;
#pragma unroll
  for (int off = 32; off >= 1; off >>= 1) {
    dv += __shfl_xor(dv, off);
    da += __shfl_xor(da, off);
  }
  if (lane == 0) {
    diag[row]      = dv;
    diag[BN + row] = da;
  }
}

// ---------------------------------------------------------------------------
// Kernel 2: partial sum_j 2^(S_ij) via mfma_f32_32x32x16_bf16.
// R12: VMEM-traffic hypothesis. R9-R11 (schedule/shape/occupancy) were ALL
// null; the one invariant across them is per-CU L1/VMEM traffic (~2.1 MB:
// every wave re-streams its own copy of B). Fix: register row-blocking t=4 —
// each wave owns FOUR 32-row tiles (128 rows) and sweeps 8 j-tiles
// (grid.y 8->32), so each B tile load feeds 4x the MFMAs. Per-wave traffic
// 132KB -> 48KB (2.76x less); MFMA/exp2/VALU totals bit-identical.
// ~220 VGPR -> 2 waves/SIMD (fine if BW-bound; R7 proved occupancy isn't
// the lever). Prediction: lse 21.3 -> 9-13 us if VMEM-bound; null => the
// serial-sum model stands and we're at the practical roofline.
// C layout (verified m74/m101): col=lane&31, row=(reg&3)+8*(reg>>2)+4*(lane>>5).
// ---------------------------------------------------------------------------
__global__ __launch_bounds__(256, 2) void lse_main(
    const unsigned short* __restrict__ Xv, const unsigned short* __restrict__ Ya,
    const unsigned short* __restrict__ Xa, const unsigned short* __restrict__ Yv,
    float* __restrict__ rowsum) {
  const unsigned short* X;
  const unsigned short* Y;
  float* rs;
  if (blockIdx.z == 0) { X = Xv; Y = Ya; rs = rowsum; }
  else                 { X = Xa; Y = Yv; rs = rowsum + BN; }

  int tid  = threadIdx.x;
  int lane = tid & 63;
  int wid  = tid >> 6;
  // first of this wave's four 32-row tiles (256 tiles total)
  int tile0 = blockIdx.x * 16 + wid * 4;

  // A fragments: 4 row-tiles x 4 K-steps, 1KB contiguous per (tile, step)
  const unsigned short* ap =
      X + (size_t)tile0 * 2048 + (size_t)lane * 8;
  bf16x8 a[4][4];
#pragma unroll
  for (int tt = 0; tt < 4; ++tt)
#pragma unroll
    for (int kk = 0; kk < 4; ++kk)
      a[tt][kk] = *(const bf16x8*)(ap + tt * 2048 + kk * 512);

  // B base: this block sweeps 8 j-tiles of 32 cols (256 cols)
  const unsigned short* bbase =
      Y + (size_t)(blockIdx.y * 8) * 2048 + (size_t)lane * 8;

  const f32x16 zero16 = {};
  f32x16 part[4] = {};
  bf16x8 b[4], bn[4];

#define LOADB(DST, T)                                                         \
  {                                                                           \
    const unsigned short* p = bbase + (size_t)(T) * 2048;                     \
    DST[0] = *(const bf16x8*)p;                                               \
    DST[1] = *(const bf16x8*)(p + 512);                                       \
    DST[2] = *(const bf16x8*)(p + 1024);                                      \
    DST[3] = *(const bf16x8*)(p + 1536);                                      \
  }
// one j-tile against all 4 row-tiles: 16 MFMA + 64 exp2/add
#define PROC(BB)                                                              \
  {                                                                           \
    _Pragma("unroll") for (int tt = 0; tt < 4; ++tt) {                        \
      f32x16 c;                                                               \
      c = __builtin_amdgcn_mfma_f32_32x32x16_bf16(a[tt][0], BB[0], zero16, 0, 0, 0); \
      c = __builtin_amdgcn_mfma_f32_32x32x16_bf16(a[tt][1], BB[1], c, 0, 0, 0); \
      c = __builtin_amdgcn_mfma_f32_32x32x16_bf16(a[tt][2], BB[2], c, 0, 0, 0); \
      c = __builtin_amdgcn_mfma_f32_32x32x16_bf16(a[tt][3], BB[3], c, 0, 0, 0); \
      _Pragma("unroll") for (int r = 0; r < 16; ++r)                          \
          part[tt][r] += __builtin_amdgcn_exp2f(c[r]);                        \
    }                                                                         \
  }

  // 8 j-tiles, alternating register buffers (no copies), loads 1 tile ahead
  LOADB(b, 0)
#pragma unroll
  for (int jj = 0; jj < 3; ++jj) {
    LOADB(bn, 2 * jj + 1)
    PROC(b)
    LOADB(b, 2 * jj + 2)
    PROC(bn)
  }
  LOADB(bn, 7)
  PROC(b)
  PROC(bn)
#undef LOADB
#undef PROC

  // row sums: reduce part[tt][r] across the 32 lanes of each half (cols)
#pragma unroll
  for (int off = 1; off < 32; off <<= 1) {
#pragma unroll
    for (int tt = 0; tt < 4; ++tt)
#pragma unroll
      for (int r = 0; r < 16; ++r)
        part[tt][r] += __shfl_xor(part[tt][r], off);
  }
  if ((lane & 31) == 0) {
    int hi = lane >> 5;
#pragma unroll
    for (int tt = 0; tt < 4; ++tt)
#pragma unroll
      for (int r = 0; r < 16; ++r) {
        int row = (r & 3) + 8 * (r >> 2) + 4 * hi;
        atomicAdd(&rs[(tile0 + tt) * 32 + row], part[tt][r]);
      }
  }
}

// ---------------------------------------------------------------------------
// Kernel 3: 64-block finalize: out += sum(ln2*log2(rowsum) - diag) / BN
// (d_out zeroed by gather_k). __builtin_amdgcn_logf IS v_log_f32 = log2.
// ---------------------------------------------------------------------------
__global__ __launch_bounds__(256) void finalize_k(
    const float* __restrict__ rowsum, const float* __restrict__ diag,
    float* __restrict__ out) {
  int i = blockIdx.x * 256 + threadIdx.x;          // 64*256 = 16384 = 2*BN
  float local = LN2 * __builtin_amdgcn_logf(rowsum[i]) - diag[i];
#pragma unroll
  for (int off = 32; off >= 1; off >>= 1) local += __shfl_xor(local, off);
  __shared__ float red[4];
  int wave = threadIdx.x >> 6;
  if ((threadIdx.x & 63) == 0) red[wave] = local;
  __syncthreads();
  if (threadIdx.x == 0) {
    float bs = red[0] + red[1] + red[2] + red[3];
    atomicAdd(out, bs * (1.f / (float)BN));
  }
}

// ---------------------------------------------------------------------------
extern "C" void kernel_launch(void* const* d_in, const int* in_sizes, int n_in,
                              void* d_out, int out_size, void* d_ws, size_t ws_size,
                              hipStream_t stream) {
  const float* a   = (const float*)d_in[0];
  const float* v   = (const float*)d_in[1];
  const int* aidx  = (const int*)d_in[2];
  const int* iidx  = (const int*)d_in[3];
  // d_in[4] = labels (unused by the loss)

  char* ws = (char*)d_ws;
  const size_t MB = 1024 * 1024;
  __hip_bfloat16* Xv = (__hip_bfloat16*)(ws + 0 * MB);
  __hip_bfloat16* Ya = (__hip_bfloat16*)(ws + 1 * MB);
  __hip_bfloat16* Xa = (__hip_bfloat16*)(ws + 2 * MB);
  __hip_bfloat16* Yv = (__hip_bfloat16*)(ws + 3 * MB);
  float* diag   = (float*)(ws + 4 * MB);             // [2][8192]
  float* rowsum = (float*)(ws + 4 * MB + 64 * 1024); // [2][8192]

  gather_k<<<BN / 4, 256, 0, stream>>>(a, v, aidx, iidx, Xv, Ya, Xa, Yv,
                                       diag, rowsum, (float*)d_out);
  // R12: t=4 register row-blocking; grid (16, 32, 2) = 1024 blocks
  lse_main<<<dim3(BN / 512, 32, 2), 256, 0, stream>>>(
      (const unsigned short*)Xv, (const unsigned short*)Ya,
      (const unsigned short*)Xa, (const unsigned short*)Yv, rowsum);
  finalize_k<<<64, 256, 0, stream>>>(rowsum, diag, (float*)d_out);
}

// Round 6
// 92.232 us; speedup vs baseline: 1.1175x; 1.1175x over previous
//
#include <hip/hip_runtime.h>
#include <hip/hip_bf16.h>

typedef __attribute__((ext_vector_type(8))) short bf16x8;   // 8 bf16 = 4 VGPRs
typedef __attribute__((ext_vector_type(4))) float f32x4;

#define BN 8192          // batch
#define DF 128           // feature dim
#define DG 64            // gathered dim
static constexpr float L2E = 1.44269504088896340736f;  // log2(e)
static constexpr float LN2 = 0.69314718055994530942f;

// Fragment-linear layout (16-row tiles, R7 scheme, restored):
// per 16-row tile (1024 shorts = 2KB): [half(2)][lane(64)][c(8)] where
// lane = q*16 + m encodes (row-in-tile m, k-group q), k = half*32 + q*8 + c.
// A wave's MFMA A/B fragment load is then base + lane*16B -> contiguous 1KB.
__device__ __forceinline__ size_t frag_off(int row, int d) {
  int tile = row >> 4, m = row & 15;
  int half = d >> 5, q = (d >> 3) & 3, c = d & 7;
  return (size_t)tile * 1024 + (size_t)half * 512 + (size_t)(q * 16 + m) * 8 + c;
}

// ---------------------------------------------------------------------------
// Kernel 1: gather columns, convert to bf16 (X-side pre-scaled by log2 e),
// write fragment-linear layout, exact fp32 diagonals, zero rowsum + d_out.
// One wave per row; coalesced float2 row loads + in-register __shfl gather.
// ---------------------------------------------------------------------------
__global__ __launch_bounds__(256) void gather_k(
    const float* __restrict__ a, const float* __restrict__ v,
    const int* __restrict__ aidx, const int* __restrict__ iidx,
    __hip_bfloat16* __restrict__ Xv, __hip_bfloat16* __restrict__ Ya,
    __hip_bfloat16* __restrict__ Xa, __hip_bfloat16* __restrict__ Yv,
    float* __restrict__ diag, float* __restrict__ rowsum,
    float* __restrict__ out) {
  int tid = threadIdx.x;
  int gid = blockIdx.x * 256 + tid;
  if (gid < 2 * BN) rowsum[gid] = 0.f;    // zero accumulators (ws is poisoned)
  if (gid == 0) out[0] = 0.f;             // d_out is poisoned too

  int lane = tid & 63;
  int row  = blockIdx.x * 4 + (tid >> 6); // 2048 blocks x 4 waves = 8192 rows
  int ka = aidx[lane];
  int ki = iidx[lane];

  // coalesced: lane l holds elements (2l, 2l+1) of this row of a and v
  float2 a2 = ((const float2*)(a + (size_t)row * DF))[lane];
  float2 v2 = ((const float2*)(v + (size_t)row * DF))[lane];

  // in-register gather: element k lives in lane k>>1, component k&1
  float axa = __shfl(a2.x, ka >> 1), aya = __shfl(a2.y, ka >> 1);
  float vxa = __shfl(v2.x, ka >> 1), vya = __shfl(v2.y, ka >> 1);
  float axi = __shfl(a2.x, ki >> 1), ayi = __shfl(a2.y, ki >> 1);
  float vxi = __shfl(v2.x, ki >> 1), vyi = __shfl(v2.y, ki >> 1);
  float aa = (ka & 1) ? aya : axa;   // audio_only        (S_v cols)
  float va = (ka & 1) ? vya : vxa;   // image_audio_only  (S_v rows)
  float ai = (ki & 1) ? ayi : axi;   // audio_image_only  (S_a rows)
  float vi = (ki & 1) ? vyi : vxi;   // image_only        (S_a cols)

  size_t fo = frag_off(row, lane);
  Xv[fo] = __float2bfloat16(va * L2E);
  Ya[fo] = __float2bfloat16(aa);
  Xa[fo] = __float2bfloat16(ai * L2E);
  Yv[fo] = __float2bfloat16(vi);

  // exact fp32 diagonals: diag_v[i] = dot(v_gath_a[i], a_gath_a[i]), etc.
  float dv = va * aa;
  float da = ai * vi;
#pragma unroll
  for (int off = 32; off >= 1; off >>= 1) {
    dv += __shfl_xor(dv, off);
    da += __shfl_xor(da, off);
  }
  if (lane == 0) {
    diag[row]      = dv;
    diag[BN + row] = da;
  }
}

// ---------------------------------------------------------------------------
// Kernel 2: partial sum_j 2^(S_ij) via mfma_f32_16x16x32_bf16.
// R13: LDS-staged B. R8 counters imply THREE partially-contended resources:
// L1 path ~68% busy (every wave privately streams ~66KB of B through L1:
// 2.1 MB/CU ~ 35k cyc), VALU+trans ~47%, MFMA ~27%, 26% no-issue (vmcnt
// convoys on the L1 path). R9/R11 rescheduled issue but left the L1 stream;
// R12 cut the stream but halved occupancy (regressed). This version stages
// B into LDS once per BLOCK (4 waves share): double-buffered 2-tile (4KB)
// steps via global_load_lds width=16, one barrier per 2 j-tiles; the
// vmcnt(0) drain is free since loads land a full compute phase early.
// Per-CU VMEM traffic 2.1 -> 0.64 MB; B reads move to the LDS pipe
// (conflict-free: consecutive lanes -> consecutive 16B). VGPR ~R7 level
// keeps 8 waves/SIMD (the thing R12 lost).
// Race ledger: writes to buf[p] in iter i happen after the barrier ending
// all iter i-1 reads of buf[p]; reads of buf[c] in iter i are protected by
// the staging wave's vmcnt(0)+barrier at the end of iter i-1.
// C layout: col = lane&15, row = quad*4 + reg.
// ---------------------------------------------------------------------------
__global__ __launch_bounds__(256, 8) void lse_main(
    const unsigned short* __restrict__ Xv, const unsigned short* __restrict__ Ya,
    const unsigned short* __restrict__ Xa, const unsigned short* __restrict__ Yv,
    float* __restrict__ rowsum) {
  const unsigned short* X;
  const unsigned short* Y;
  float* rs;
  if (blockIdx.z == 0) { X = Xv; Y = Ya; rs = rowsum; }
  else                 { X = Xa; Y = Yv; rs = rowsum + BN; }

  __shared__ __align__(16) unsigned short sB[2][2048];  // 2 bufs x 2 tiles x 2KB

  int tid  = threadIdx.x;
  int lane = tid & 63;
  int wid  = tid >> 6;
  int m = lane & 15;        // C: col within j-tile
  int q = lane >> 4;        // C: row group
  int row0 = blockIdx.x * 128 + wid * 32;          // 2 row-tiles per wave

  // A fragments for this wave's 2 row-tiles (K=64 -> 2 halves per tile)
  bf16x8 af[2][2];
#pragma unroll
  for (int t = 0; t < 2; ++t) {
    const unsigned short* p =
        X + (size_t)(row0 / 16 + t) * 1024 + (size_t)lane * 8;
    af[t][0] = *(const bf16x8*)p;
    af[t][1] = *(const bf16x8*)(p + 512);
  }

  // block's B stripe: 32 j-tiles of 1024 shorts (512 cols)
  const unsigned short* bblock = Y + (size_t)(blockIdx.y * 32) * 1024;

  // stage tile-pair PAIR (2 tiles = 4KB) into sB[BUF]; each wave moves 1KB.
  // source is linear in our fragment layout, dest is linear in LDS -> the
  // wave-uniform-base + lane*16 contract of global_load_lds holds.
#define STAGE(PAIR, BUF)                                                      \
  __builtin_amdgcn_global_load_lds(                                           \
      (const __attribute__((address_space(1))) void*)(                        \
          bblock + (size_t)(PAIR) * 2048 + wid * 512 + lane * 8),             \
      (__attribute__((address_space(3))) void*)(                              \
          &sB[BUF][wid * 512 + lane * 8]),                                    \
      16, 0, 0);

  f32x4 part[2] = {};
  const f32x4 zero = {0.f, 0.f, 0.f, 0.f};

  // prologue: stage pair 0 (tiles 0,1) into buf 0
  STAGE(0, 0)
  asm volatile("s_waitcnt vmcnt(0)" ::: "memory");
  __syncthreads();

  for (int i = 0; i < 16; ++i) {
    int cur = i & 1;
    // B fragments for tiles 2i, 2i+1 from LDS (ds_read_b128, conflict-free)
    bf16x8 b[2][2];
#pragma unroll
    for (int tt = 0; tt < 2; ++tt) {
      b[tt][0] = *(const bf16x8*)&sB[cur][tt * 1024 + lane * 8];
      b[tt][1] = *(const bf16x8*)&sB[cur][tt * 1024 + 512 + lane * 8];
    }
    // stage next pair while computing this one
    if (i < 15) STAGE(i + 1, cur ^ 1)
#pragma unroll
    for (int tt = 0; tt < 2; ++tt) {
#pragma unroll
      for (int t = 0; t < 2; ++t) {
        f32x4 c =
            __builtin_amdgcn_mfma_f32_16x16x32_bf16(af[t][0], b[tt][0], zero, 0, 0, 0);
        c = __builtin_amdgcn_mfma_f32_16x16x32_bf16(af[t][1], b[tt][1], c, 0, 0, 0);
        f32x4 e;
        e[0] = __builtin_amdgcn_exp2f(c[0]);
        e[1] = __builtin_amdgcn_exp2f(c[1]);
        e[2] = __builtin_amdgcn_exp2f(c[2]);
        e[3] = __builtin_amdgcn_exp2f(c[3]);
        part[t] += e;
      }
    }
    asm volatile("s_waitcnt vmcnt(0)" ::: "memory");  // staged loads landed long ago
    __syncthreads();
  }
#undef STAGE

  // row sums are spread across the 16 lanes of each quad -> xor-shuffle reduce
#pragma unroll
  for (int off = 1; off < 16; off <<= 1) {
#pragma unroll
    for (int t = 0; t < 2; ++t) {
#pragma unroll
      for (int r = 0; r < 4; ++r)
        part[t][r] += __shfl_xor(part[t][r], off);
    }
  }
  if (m == 0) {
#pragma unroll
    for (int t = 0; t < 2; ++t)
#pragma unroll
      for (int r = 0; r < 4; ++r)
        atomicAdd(&rs[row0 + t * 16 + q * 4 + r], part[t][r]);
  }
}

// ---------------------------------------------------------------------------
// Kernel 3: 64-block finalize: out += sum(ln2*log2(rowsum) - diag) / BN
// (d_out zeroed by gather_k). __builtin_amdgcn_logf IS v_log_f32 = log2.
// ---------------------------------------------------------------------------
__global__ __launch_bounds__(256) void finalize_k(
    const float* __restrict__ rowsum, const float* __restrict__ diag,
    float* __restrict__ out) {
  int i = blockIdx.x * 256 + threadIdx.x;          // 64*256 = 16384 = 2*BN
  float local = LN2 * __builtin_amdgcn_logf(rowsum[i]) - diag[i];
#pragma unroll
  for (int off = 32; off >= 1; off >>= 1) local += __shfl_xor(local, off);
  __shared__ float red[4];
  int wave = threadIdx.x >> 6;
  if ((threadIdx.x & 63) == 0) red[wave] = local;
  __syncthreads();
  if (threadIdx.x == 0) {
    float bs = red[0] + red[1] + red[2] + red[3];
    atomicAdd(out, bs * (1.f / (float)BN));
  }
}

// ---------------------------------------------------------------------------
extern "C" void kernel_launch(void* const* d_in, const int* in_sizes, int n_in,
                              void* d_out, int out_size, void* d_ws, size_t ws_size,
                              hipStream_t stream) {
  const float* a   = (const float*)d_in[0];
  const float* v   = (const float*)d_in[1];
  const int* aidx  = (const int*)d_in[2];
  const int* iidx  = (const int*)d_in[3];
  // d_in[4] = labels (unused by the loss)

  char* ws = (char*)d_ws;
  const size_t MB = 1024 * 1024;
  __hip_bfloat16* Xv = (__hip_bfloat16*)(ws + 0 * MB);
  __hip_bfloat16* Ya = (__hip_bfloat16*)(ws + 1 * MB);
  __hip_bfloat16* Xa = (__hip_bfloat16*)(ws + 2 * MB);
  __hip_bfloat16* Yv = (__hip_bfloat16*)(ws + 3 * MB);
  float* diag   = (float*)(ws + 4 * MB);             // [2][8192]
  float* rowsum = (float*)(ws + 4 * MB + 64 * 1024); // [2][8192]

  gather_k<<<BN / 4, 256, 0, stream>>>(a, v, aidx, iidx, Xv, Ya, Xa, Yv,
                                       diag, rowsum, (float*)d_out);
  lse_main<<<dim3(BN / 128, 16, 2), 256, 0, stream>>>(
      (const unsigned short*)Xv, (const unsigned short*)Ya,
      (const unsigned short*)Xa, (const unsigned short*)Yv, rowsum);
  finalize_k<<<64, 256, 0, stream>>>(rowsum, diag, (float*)d_out);
}